// Round 5
// baseline (4226.926 us; speedup 1.0000x reference)
//
#include <hip/hip_runtime.h>
#include <stdint.h>
#include <math.h>

#define NANCH 261888
#define NBATCH 16
#define PRE_NMS 12000
#define POST_NMS 2000
#define NSLOT 24          // 512 threads * 24 = 12288 slots >= 12000
#define MASKW 384         // 12288 bits / 32
#define BCACHE 9216       // boxes cached in LDS (144 KB)
#define KACC 8            // selections per super-round

// ---------- key construction: (ordered score bits << 32) | ~index ----------
__device__ __forceinline__ uint64_t make_key(float s, int i) {
    uint32_t u = __float_as_uint(s);
    u ^= (u >> 31) ? 0xFFFFFFFFu : 0x80000000u;   // total order for floats
    return ((uint64_t)u << 32) | (uint32_t)(~(uint32_t)i);
}

// ---------- init ----------
__global__ void k_init(uint32_t* hist, uint64_t* prefix, uint32_t* kth, uint32_t* cnt) {
    int tid = threadIdx.x;
    for (int i = tid; i < NBATCH * 256; i += blockDim.x) hist[i] = 0;
    if (tid < NBATCH) { prefix[tid] = 0; kth[tid] = PRE_NMS; cnt[tid] = 0; }
}

// ---------- radix-select histogram pass over 8-bit digits, MSB first ----------
__global__ void k_hist(const float* __restrict__ scores, uint32_t* __restrict__ hist,
                       const uint64_t* __restrict__ prefix, int pass) {
    __shared__ uint32_t lh[256];
    int tid = threadIdx.x;
    int b = blockIdx.y;
    lh[tid] = 0;
    __syncthreads();
    uint64_t pfx = prefix[b];
    int sp = 64 - 8 * pass;
    int sd = 56 - 8 * pass;
    const float* sc = scores + (size_t)b * NANCH;
    for (int i = blockIdx.x * 256 + tid; i < NANCH; i += gridDim.x * 256) {
        uint64_t key = make_key(sc[i], i);
        bool cand = (pass == 0) || ((key >> sp) == (pfx >> sp));
        if (cand) atomicAdd(&lh[(uint32_t)(key >> sd) & 0xFFu], 1u);
    }
    __syncthreads();
    uint32_t c = lh[tid];
    if (c) atomicAdd(&hist[b * 256 + tid], c);
}

// ---------- pick digit containing kth largest; reset hist ----------
__global__ void k_pick(uint32_t* hist, uint64_t* prefix, uint32_t* kth, int pass) {
    __shared__ uint32_t h[256];
    int tid = threadIdx.x;
    int b = blockIdx.x;
    h[tid] = hist[b * 256 + tid];
    hist[b * 256 + tid] = 0;
    __syncthreads();
    if (tid == 0) {
        uint32_t k = kth[b];
        uint32_t cum = 0;
        int d = 255;
        for (; d > 0; --d) {
            uint32_t c = h[d];
            if (cum + c >= k) break;
            cum += c;
        }
        kth[b] = k - cum;
        prefix[b] |= ((uint64_t)(uint32_t)d) << (56 - 8 * pass);
    }
}

// ---------- compact: wave-aggregated LDS staging, 1 global atomic per block ----
__global__ __launch_bounds__(256) void k_compact(const float* __restrict__ scores,
                                                 const uint64_t* __restrict__ prefix,
                                                 uint32_t* __restrict__ cnt,
                                                 uint64_t* __restrict__ selk) {
    __shared__ uint32_t lcnt, lbase;
    __shared__ uint64_t lbuf[2048];
    int tid = threadIdx.x;
    int b = blockIdx.y;
    int ln = tid & 63;
    if (tid == 0) lcnt = 0;
    __syncthreads();
    uint64_t T = prefix[b];
    const float* sc = scores + (size_t)b * NANCH;
    int base0 = blockIdx.x * 2048;
    for (int r = 0; r < 8; ++r) {
        int i = base0 + r * 256 + tid;
        bool pred = false;
        uint64_t key = 0;
        if (i < NANCH) { key = make_key(sc[i], i); pred = key >= T; }
        unsigned long long bal = __ballot(pred);
        uint32_t wb = 0;
        if (ln == 0 && bal) wb = atomicAdd(&lcnt, (uint32_t)__popcll(bal));
        wb = __shfl(wb, 0);
        if (pred) lbuf[wb + (uint32_t)__popcll(bal & ((1ull << ln) - 1ull))] = key;
    }
    __syncthreads();
    if (tid == 0) lbase = atomicAdd(&cnt[b], lcnt);
    __syncthreads();
    uint32_t n = lcnt, bs = lbase;
    for (uint32_t i = tid; i < n; i += 256) {
        uint32_t p = bs + i;
        if (p < PRE_NMS) selk[(size_t)b * PRE_NMS + p] = lbuf[i];
    }
}

// ---------- rank sort: rank = #{keys > mine}; scatter anchor idx to rank -----
#define RNK_RPT 4
__global__ void k_rank(const uint64_t* __restrict__ selk, uint32_t* __restrict__ aidx) {
    __shared__ uint64_t ch[2048];
    int tid = threadIdx.x;
    int b = blockIdx.y;
    const uint64_t* keys = selk + (size_t)b * PRE_NMS;
    uint64_t mine[RNK_RPT];
    int rank[RNK_RPT];
    int base = blockIdx.x * (256 * RNK_RPT) + tid;
    #pragma unroll
    for (int r = 0; r < RNK_RPT; ++r) {
        int e = base + r * 256;
        mine[r] = (e < PRE_NMS) ? keys[e] : 0;
        rank[r] = 0;
    }
    for (int c0 = 0; c0 < PRE_NMS; c0 += 2048) {
        for (int j = tid; j < 2048; j += 256) {
            int g = c0 + j;
            ch[j] = (g < PRE_NMS) ? keys[g] : 0;
        }
        __syncthreads();
        #pragma unroll 8
        for (int j = 0; j < 2048; ++j) {
            uint64_t kj = ch[j];
            #pragma unroll
            for (int r = 0; r < RNK_RPT; ++r) rank[r] += (kj > mine[r]) ? 1 : 0;
        }
        __syncthreads();
    }
    #pragma unroll
    for (int r = 0; r < RNK_RPT; ++r) {
        int e = base + r * 256;
        if (e < PRE_NMS) aidx[(size_t)b * PRE_NMS + rank[r]] = ~(uint32_t)(mine[r] & 0xFFFFFFFFull);
    }
}

// ---------- spatial counting-sort of ranks by (level, 64px tile Morton) ------
__global__ __launch_bounds__(1024) void k_spatsort(const uint32_t* __restrict__ aidx,
                                                   uint32_t* __restrict__ spat2rank) {
    __shared__ uint32_t hist[2048];
    __shared__ uint32_t wsum[16];
    int b = blockIdx.x, tid = threadIdx.x;
    int wv = tid >> 6, ln = tid & 63;
    for (int i = tid; i < 2048; i += 1024) hist[i] = 0;
    __syncthreads();
    uint32_t sk[12];
    #pragma unroll
    for (int j = 0; j < 12; ++j) {
        int i = tid + 1024 * j;
        sk[j] = 0;
        if (i < PRE_NMS) {
            uint32_t a = aidx[(size_t)b * PRE_NMS + i];
            uint32_t level, base, lw, sh;
            if (a < 196608)      { level = 0; base = 0;      lw = 8; sh = 2; }
            else if (a < 245760) { level = 1; base = 196608; lw = 7; sh = 3; }
            else if (a < 258048) { level = 2; base = 245760; lw = 6; sh = 4; }
            else if (a < 261120) { level = 3; base = 258048; lw = 5; sh = 5; }
            else                 { level = 4; base = 261120; lw = 4; sh = 6; }
            uint32_t cell = (a - base) / 3u;
            uint32_t x = cell & ((1u << lw) - 1u);
            uint32_t y = cell >> lw;
            uint32_t tx = (x << sh) >> 6, ty = (y << sh) >> 6;   // 0..15
            uint32_t mx = (tx | (tx << 2)) & 0x33u; mx = (mx | (mx << 1)) & 0x55u;
            uint32_t my = (ty | (ty << 2)) & 0x33u; my = (my | (my << 1)) & 0x55u;
            uint32_t key = (level << 8) | mx | (my << 1);
            sk[j] = key;
            atomicAdd(&hist[key], 1u);
        }
    }
    __syncthreads();
    uint32_t v0 = hist[2 * tid], v1 = hist[2 * tid + 1];
    uint32_t tot = v0 + v1;
    uint32_t inc = tot;
    for (int d = 1; d < 64; d <<= 1) {
        uint32_t t = __shfl_up(inc, d);
        if (ln >= d) inc += t;
    }
    if (ln == 63) wsum[wv] = inc;
    __syncthreads();
    uint32_t wbase = 0;
    for (int w = 0; w < 16; ++w) wbase += (w < wv) ? wsum[w] : 0u;
    uint32_t excl = wbase + inc - tot;
    __syncthreads();
    hist[2 * tid] = excl;
    hist[2 * tid + 1] = excl + v0;
    __syncthreads();
    #pragma unroll
    for (int j = 0; j < 12; ++j) {
        int i = tid + 1024 * j;
        if (i < PRE_NMS) {
            uint32_t pos = atomicAdd(&hist[sk[j]], 1u);
            spat2rank[(size_t)b * PRE_NMS + pos] = (uint32_t)i;
        }
    }
}

// ---------- gather + bbox decode + clip (rank order) ----------
__global__ void k_gather(const float4* __restrict__ anchors, const float4* __restrict__ deltas,
                         const float* __restrict__ im_info, const uint32_t* __restrict__ aidx,
                         float4* __restrict__ props) {
    int b = blockIdx.y;
    int i = blockIdx.x * 256 + threadIdx.x;
    if (i >= PRE_NMS) return;
    uint32_t a = aidx[(size_t)b * PRE_NMS + i];
    float4 an = anchors[a];
    float4 dl = deltas[(size_t)b * NANCH + a];
    float w  = __fadd_rn(__fsub_rn(an.z, an.x), 1.0f);
    float h  = __fadd_rn(__fsub_rn(an.w, an.y), 1.0f);
    float cx = __fadd_rn(an.x, __fmul_rn(0.5f, w));
    float cy = __fadd_rn(an.y, __fmul_rn(0.5f, h));
    float pcx = __fadd_rn(__fmul_rn(dl.x, w), cx);
    float pcy = __fadd_rn(__fmul_rn(dl.y, h), cy);
    float ew = (float)exp((double)dl.z);
    float eh = (float)exp((double)dl.w);
    float pw = __fmul_rn(ew, w);
    float ph = __fmul_rn(eh, h);
    float x1 = __fsub_rn(pcx, __fmul_rn(0.5f, pw));
    float y1 = __fsub_rn(pcy, __fmul_rn(0.5f, ph));
    float x2 = __fadd_rn(pcx, __fmul_rn(0.5f, pw));
    float y2 = __fadd_rn(pcy, __fmul_rn(0.5f, ph));
    float xmax = __fsub_rn(im_info[b * 3 + 1], 1.0f);
    float ymax = __fsub_rn(im_info[b * 3 + 0], 1.0f);
    x1 = fminf(fmaxf(x1, 0.0f), xmax);
    y1 = fminf(fmaxf(y1, 0.0f), ymax);
    x2 = fminf(fmaxf(x2, 0.0f), xmax);
    y2 = fminf(fmaxf(y2, 0.0f), ymax);
    props[(size_t)b * PRE_NMS + i] = make_float4(x1, y1, x2, y2);
}

// ---------- greedy NMS: batched super-rounds, up to KACC accepted per round ---
// Round = phase1 (consistent mask snapshot: extract next 8 set bits, batch-load
// boxes, in-register greedy accept/reject) | barrier | phase2 (combined kill
// pass for accepted; atomic mask clears) | barrier. Output deferred to epilogue.
// Determinism: phase1 sees a mutation-free mask; rejected candidates are
// provably cleared in phase2 (killer overlaps them => gate passes, exact test);
// accepted bits never cleared (self-guard; IoU(acc_i,acc_j)<=thr by constr.).
// Exact div-free IoU: div_rn(i,d) <= 0.7f  <=>  (double)i < MD*(double)d.
__global__ __launch_bounds__(512) void k_nms(const float4* __restrict__ props,
                                             const uint32_t* __restrict__ s2r,
                                             float* __restrict__ out) {
    const double MD = (double)0.7f + 2.9802322387695312e-08;   // 0.7f + 2^-25
    int b = blockIdx.x;
    int tid = threadIdx.x;
    int wv = tid >> 6, ln = tid & 63;
    const float4* P = props + (size_t)b * PRE_NMS;
    const uint32_t* SR = s2r + (size_t)b * PRE_NMS;

    __shared__ uint32_t mask[MASKW];
    __shared__ float4 bc[BCACHE];
    __shared__ unsigned short sels[2048];
    for (int i = tid; i < MASKW; i += 512) mask[i] = (i < (PRE_NMS / 32)) ? 0xFFFFFFFFu : 0u;
    for (int i = tid; i < BCACHE; i += 512) bc[i] = P[i];

    float bx1[NSLOT], by1[NSLOT], bx2[NSLOT], by2[NSLOT];
    uint32_t rrp[NSLOT / 2];   // packed ranks, 2 x u16 per reg
    uint32_t vm = 0;
    #pragma unroll
    for (int j = 0; j < NSLOT / 2; ++j) rrp[j] = 0;
    #pragma unroll
    for (int j = 0; j < NSLOT; ++j) {
        int sp = (wv * NSLOT + j) * 64 + ln;
        bx1[j] = 1.0e30f; by1[j] = 1.0e30f; bx2[j] = -1.0e30f; by2[j] = -1.0e30f;
        if (sp < PRE_NMS) {
            int r = (int)SR[sp];
            rrp[j >> 1] |= ((uint32_t)r) << ((j & 1) * 16);
            float4 p = P[r];
            bx1[j] = p.x; by1[j] = p.y; bx2[j] = p.z; by2[j] = p.w;
            vm |= 1u << j;
        }
    }
    // lane g (g < NSLOT) keeps group g's bbox (x1min, y1min, x2max+1, y2max+1)
    float gx1 = 1.0e30f, gy1 = 1.0e30f, gx2p = -1.0e30f, gy2p = -1.0e30f;
    #pragma unroll
    for (int j = 0; j < NSLOT; ++j) {
        float a1 = bx1[j], c1 = by1[j], a2 = bx2[j], c2 = by2[j];
        for (int d = 1; d < 64; d <<= 1) {
            a1 = fminf(a1, __shfl_xor(a1, d));
            c1 = fminf(c1, __shfl_xor(c1, d));
            a2 = fmaxf(a2, __shfl_xor(a2, d));
            c2 = fmaxf(c2, __shfl_xor(c2, d));
        }
        if (ln == j) { gx1 = a1; gy1 = c1; gx2p = a2 + 1.0f; gy2p = c2 + 1.0f; }
    }

    int nsel = 0, scanb = 0;
    __syncthreads();

    // exact kill test of slot j vs uniform box (qx1..qy2, area qa); true = kill
    auto kill_test = [&](float qx1, float qy1, float qx2, float qy2, float qa, int j) -> bool {
        float xx1 = fmaxf(qx1, bx1[j]);
        float yy1 = fmaxf(qy1, by1[j]);
        float xx2 = fminf(qx2, bx2[j]);
        float yy2 = fminf(qy2, by2[j]);
        float ww2 = fmaxf(__fadd_rn(__fsub_rn(xx2, xx1), 1.0f), 0.0f);
        float hh2 = fmaxf(__fadd_rn(__fsub_rn(yy2, yy1), 1.0f), 0.0f);
        float inter = __fmul_rn(ww2, hh2);
        float ab = __fmul_rn(__fadd_rn(__fsub_rn(bx2[j], bx1[j]), 1.0f),
                             __fadd_rn(__fsub_rn(by2[j], by1[j]), 1.0f));
        float denom = __fsub_rn(__fadd_rn(qa, ab), inter);
        return !((double)inter < MD * (double)denom);
    };

    while (nsel < POST_NMS) {
        // ================= PHASE 1: snapshot walk =================
        int w0 = scanb >> 5;
        uint32_t wd;
        {
            int w = w0 + ln;
            wd = (w < MASKW) ? mask[w] : 0u;
            if (ln == 0) wd &= (0xFFFFFFFFu << (scanb & 31));
        }
        int cs[KACC];
        int cnum = 0;
        #pragma unroll
        for (int k = 0; k < KACC; ++k) cs[k] = 0;
        while (cnum < KACC) {
            unsigned long long bal = __ballot(wd != 0u);
            if (!bal) {
                w0 += 64;
                if (w0 >= MASKW) break;
                int w = w0 + ln;
                wd = (w < MASKW) ? mask[w] : 0u;
                continue;
            }
            int L = __ffsll(bal) - 1;
            uint32_t wsel = (uint32_t)__builtin_amdgcn_readlane((int)wd, L);
            int c = ((w0 + L) << 5) + (__ffs(wsel) - 1);
            #pragma unroll
            for (int k = 0; k < KACC; ++k) if (cnum == k) cs[k] = c;
            cnum++;
            if (ln == L) wd &= (wd - 1);
        }
        if (cnum == 0) break;   // mask exhausted

        // batch-load candidate boxes (uniform broadcast reads) + areas
        float4 cb[KACC];
        float car[KACC];
        #pragma unroll
        for (int k = 0; k < KACC; ++k) {
            cb[k] = make_float4(0.f, 0.f, 0.f, 0.f);
            if (k < cnum) cb[k] = (cs[k] < BCACHE) ? bc[cs[k]] : P[cs[k]];
        }
        #pragma unroll
        for (int k = 0; k < KACC; ++k)
            car[k] = __fmul_rn(__fadd_rn(__fsub_rn(cb[k].z, cb[k].x), 1.0f),
                               __fadd_rn(__fsub_rn(cb[k].w, cb[k].y), 1.0f));

        // in-register greedy accept/reject (all lanes redundant, deterministic)
        bool accf[KACC];
        int nacc = 0;
        int navail = POST_NMS - nsel;
        #pragma unroll
        for (int j = 0; j < KACC; ++j) {
            bool ok = (j < cnum) && (nacc < navail);
            #pragma unroll
            for (int i = 0; i < KACC; ++i) {
                if (i < j && accf[i]) {
                    float xx1 = fmaxf(cb[i].x, cb[j].x);
                    float yy1 = fmaxf(cb[i].y, cb[j].y);
                    float xx2 = fminf(cb[i].z, cb[j].z);
                    float yy2 = fminf(cb[i].w, cb[j].w);
                    float ww2 = fmaxf(__fadd_rn(__fsub_rn(xx2, xx1), 1.0f), 0.0f);
                    float hh2 = fmaxf(__fadd_rn(__fsub_rn(yy2, yy1), 1.0f), 0.0f);
                    float inter = __fmul_rn(ww2, hh2);
                    float denom = __fsub_rn(__fadd_rn(car[i], car[j]), inter);
                    if (!((double)inter < MD * (double)denom)) ok = false;
                }
            }
            accf[j] = ok;
            if (ok) nacc++;
        }
        // record accepted (thread 0), advance counters
        if (tid == 0) {
            int p = 0;
            #pragma unroll
            for (int j = 0; j < KACC; ++j) {
                if (accf[j]) { sels[nsel + p] = (unsigned short)cs[j]; p++; }
            }
        }
        nsel += nacc;
        int lastex = 0;
        #pragma unroll
        for (int k = 0; k < KACC; ++k) if (k == cnum - 1) lastex = cs[k];
        scanb = lastex + 1;
        __syncthreads();   // barrier A: all snapshot reads done

        // ================= PHASE 2: combined kill pass =================
        uint32_t todos[KACC];
        uint32_t tAll = 0;
        #pragma unroll
        for (int jj = 0; jj < KACC; ++jj) {
            todos[jj] = 0;
            if (jj < cnum && accf[jj]) {
                float sx2p = __fadd_rn(cb[jj].z, 1.0f);
                float sy2p = __fadd_rn(cb[jj].w, 1.0f);
                bool ovl = (ln < NSLOT) &&
                           !((gx1 >= sx2p) || (gx2p <= cb[jj].x) ||
                             (gy1 >= sy2p) || (gy2p <= cb[jj].y));
                todos[jj] = (uint32_t)__ballot(ovl);
                tAll |= todos[jj];
            }
        }
        if (tAll) {
            #pragma unroll
            for (int j = 0; j < NSLOT; ++j) {
                if ((tAll >> j) & 1u) {           // wave-uniform -> scalar branch
                    if ((vm >> j) & 1u) {
                        int r = (int)((rrp[j >> 1] >> ((j & 1) * 16)) & 0xFFFFu);
                        bool dead = false;
                        #pragma unroll
                        for (int jj = 0; jj < KACC; ++jj) {
                            if (!dead && ((todos[jj] >> j) & 1u) && r != cs[jj])
                                dead = kill_test(cb[jj].x, cb[jj].y, cb[jj].z, cb[jj].w,
                                                 car[jj], j);
                        }
                        if (dead) {
                            vm &= ~(1u << j);
                            atomicAnd(&mask[r >> 5], ~(1u << (r & 31)));
                        }
                    }
                }
            }
        }
        __syncthreads();   // barrier B: kills visible before next snapshot
    }

    // ================= epilogue: write all output rows =================
    float* outb = out + (size_t)b * POST_NMS * 5;
    for (int r = tid; r < POST_NMS; r += 512) {
        float* row = outb + (size_t)r * 5;
        if (r < nsel) {
            int s = (int)sels[r];
            float4 p = (s < BCACHE) ? bc[s] : P[s];
            row[0] = (float)b; row[1] = p.x; row[2] = p.y; row[3] = p.z; row[4] = p.w;
        } else {
            row[0] = (float)b; row[1] = 0.0f; row[2] = 0.0f; row[3] = 0.0f; row[4] = 0.0f;
        }
    }
}

extern "C" void kernel_launch(void* const* d_in, const int* in_sizes, int n_in,
                              void* d_out, int out_size, void* d_ws, size_t ws_size,
                              hipStream_t stream) {
    const float* scores  = (const float*)d_in[0];
    const float* deltas  = (const float*)d_in[1];
    const float* im_info = (const float*)d_in[2];
    const float* anchors = (const float*)d_in[3];
    float* out = (float*)d_out;

    uint8_t* w = (uint8_t*)d_ws;
    uint32_t* hist      = (uint32_t*)(w);                    // 16384 B
    uint64_t* prefix    = (uint64_t*)(w + 16384);            // 128 B
    uint32_t* kth       = (uint32_t*)(w + 16512);            // 64 B
    uint32_t* cnt       = (uint32_t*)(w + 16576);            // 64 B
    uint64_t* selk      = (uint64_t*)(w + 16640);            // 1,536,000 B
    uint32_t* aidx      = (uint32_t*)(w + 1552640);          // 768,000 B
    float*    props     = (float*)(w + 2320640);             // 3,072,000 B
    uint32_t* spat2rank = (uint32_t*)(w + 5392640);          // 768,000 B (end 6,160,640)

    hipLaunchKernelGGL(k_init, dim3(1), dim3(1024), 0, stream, hist, prefix, kth, cnt);
    for (int p = 0; p < 8; ++p) {
        hipLaunchKernelGGL(k_hist, dim3(128, NBATCH), dim3(256), 0, stream, scores, hist, prefix, p);
        hipLaunchKernelGGL(k_pick, dim3(NBATCH), dim3(256), 0, stream, hist, prefix, kth, p);
    }
    hipLaunchKernelGGL(k_compact, dim3(128, NBATCH), dim3(256), 0, stream, scores, prefix, cnt, selk);
    hipLaunchKernelGGL(k_rank, dim3(12, NBATCH), dim3(256), 0, stream, selk, aidx);
    hipLaunchKernelGGL(k_spatsort, dim3(NBATCH), dim3(1024), 0, stream, aidx, spat2rank);
    hipLaunchKernelGGL(k_gather, dim3(47, NBATCH), dim3(256), 0, stream,
                       (const float4*)anchors, (const float4*)deltas, im_info, aidx,
                       (float4*)props);
    hipLaunchKernelGGL(k_nms, dim3(NBATCH), dim3(512), 0, stream,
                       (const float4*)props, spat2rank, out);
}

// Round 6
// 902.672 us; speedup vs baseline: 4.6827x; 4.6827x over previous
//
#include <hip/hip_runtime.h>
#include <stdint.h>
#include <math.h>

#define NANCH 261888
#define NBATCH 16
#define PRE_NMS 12000
#define POST_NMS 2000
#define NBINS 21845        // sum of 8 grids: 128^2+64^2+...+1
#define BINCAP 98304       // per-batch bin-list entry capacity
#define ADJCAP 131072      // per-batch adjacency entry capacity
#define NCHUNK 188         // ceil(12000/64)

// ---------- key construction: (ordered score bits << 32) | ~index ----------
__device__ __forceinline__ uint64_t make_key(float s, int i) {
    uint32_t u = __float_as_uint(s);
    u ^= (u >> 31) ? 0xFFFFFFFFu : 0x80000000u;   // total order for floats
    return ((uint64_t)u << 32) | (uint32_t)(~(uint32_t)i);
}

// exact kill test: div_rn(inter,denom) > 0.7f  (proven exact, absmax=0 r2-r5)
__device__ __forceinline__ bool kill_pair(float4 a, float4 c) {
    const double MD = (double)0.7f + 2.9802322387695312e-08;   // 0.7f + 2^-25
    float xx1 = fmaxf(a.x, c.x), yy1 = fmaxf(a.y, c.y);
    float xx2 = fminf(a.z, c.z), yy2 = fminf(a.w, c.w);
    float ww = fmaxf(__fadd_rn(__fsub_rn(xx2, xx1), 1.0f), 0.0f);
    float hh = fmaxf(__fadd_rn(__fsub_rn(yy2, yy1), 1.0f), 0.0f);
    float inter = __fmul_rn(ww, hh);
    float aa = __fmul_rn(__fadd_rn(__fsub_rn(a.z, a.x), 1.0f),
                         __fadd_rn(__fsub_rn(a.w, a.y), 1.0f));
    float ab = __fmul_rn(__fadd_rn(__fsub_rn(c.z, c.x), 1.0f),
                         __fadd_rn(__fsub_rn(c.w, c.y), 1.0f));
    float denom = __fsub_rn(__fadd_rn(aa, ab), inter);
    return !((double)inter < MD * (double)denom);
}

// ---------- init: zero hist + bin counters ----------
__global__ void k_init(uint32_t* hist, uint64_t* prefix, uint32_t* kth, uint32_t* cnt,
                       uint32_t* bincnt) {
    int tid = blockIdx.x * 256 + threadIdx.x;
    for (int i = tid; i < NBATCH * 256; i += gridDim.x * 256) hist[i] = 0;
    for (int i = tid; i < NBATCH * NBINS; i += gridDim.x * 256) bincnt[i] = 0;
    if (tid < NBATCH) { prefix[tid] = 0; kth[tid] = PRE_NMS; cnt[tid] = 0; }
}

// ---------- radix-select histogram pass over 8-bit digits, MSB first ----------
__global__ void k_hist(const float* __restrict__ scores, uint32_t* __restrict__ hist,
                       const uint64_t* __restrict__ prefix, int pass) {
    __shared__ uint32_t lh[256];
    int tid = threadIdx.x;
    int b = blockIdx.y;
    lh[tid] = 0;
    __syncthreads();
    uint64_t pfx = prefix[b];
    int sp = 64 - 8 * pass;
    int sd = 56 - 8 * pass;
    const float* sc = scores + (size_t)b * NANCH;
    for (int i = blockIdx.x * 256 + tid; i < NANCH; i += gridDim.x * 256) {
        uint64_t key = make_key(sc[i], i);
        bool cand = (pass == 0) || ((key >> sp) == (pfx >> sp));
        if (cand) atomicAdd(&lh[(uint32_t)(key >> sd) & 0xFFu], 1u);
    }
    __syncthreads();
    uint32_t c = lh[tid];
    if (c) atomicAdd(&hist[b * 256 + tid], c);
}

// ---------- pick digit containing kth largest; reset hist ----------
__global__ void k_pick(uint32_t* hist, uint64_t* prefix, uint32_t* kth, int pass) {
    __shared__ uint32_t h[256];
    int tid = threadIdx.x;
    int b = blockIdx.x;
    h[tid] = hist[b * 256 + tid];
    hist[b * 256 + tid] = 0;
    __syncthreads();
    if (tid == 0) {
        uint32_t k = kth[b];
        uint32_t cum = 0;
        int d = 255;
        for (; d > 0; --d) {
            uint32_t c = h[d];
            if (cum + c >= k) break;
            cum += c;
        }
        kth[b] = k - cum;
        prefix[b] |= ((uint64_t)(uint32_t)d) << (56 - 8 * pass);
    }
}

// ---------- compact: wave-aggregated LDS staging, 1 global atomic per block ----
__global__ __launch_bounds__(256) void k_compact(const float* __restrict__ scores,
                                                 const uint64_t* __restrict__ prefix,
                                                 uint32_t* __restrict__ cnt,
                                                 uint64_t* __restrict__ selk) {
    __shared__ uint32_t lcnt, lbase;
    __shared__ uint64_t lbuf[2048];
    int tid = threadIdx.x;
    int b = blockIdx.y;
    int ln = tid & 63;
    if (tid == 0) lcnt = 0;
    __syncthreads();
    uint64_t T = prefix[b];
    const float* sc = scores + (size_t)b * NANCH;
    int base0 = blockIdx.x * 2048;
    for (int r = 0; r < 8; ++r) {
        int i = base0 + r * 256 + tid;
        bool pred = false;
        uint64_t key = 0;
        if (i < NANCH) { key = make_key(sc[i], i); pred = key >= T; }
        unsigned long long bal = __ballot(pred);
        uint32_t wb = 0;
        if (ln == 0 && bal) wb = atomicAdd(&lcnt, (uint32_t)__popcll(bal));
        wb = __shfl(wb, 0);
        if (pred) lbuf[wb + (uint32_t)__popcll(bal & ((1ull << ln) - 1ull))] = key;
    }
    __syncthreads();
    if (tid == 0) lbase = atomicAdd(&cnt[b], lcnt);
    __syncthreads();
    uint32_t n = lcnt, bs = lbase;
    for (uint32_t i = tid; i < n; i += 256) {
        uint32_t p = bs + i;
        if (p < PRE_NMS) selk[(size_t)b * PRE_NMS + p] = lbuf[i];
    }
}

// ---------- rank sort: rank = #{keys > mine}; scatter anchor idx to rank -----
#define RNK_RPT 4
__global__ void k_rank(const uint64_t* __restrict__ selk, uint32_t* __restrict__ aidx) {
    __shared__ uint64_t ch[2048];
    int tid = threadIdx.x;
    int b = blockIdx.y;
    const uint64_t* keys = selk + (size_t)b * PRE_NMS;
    uint64_t mine[RNK_RPT];
    int rank[RNK_RPT];
    int base = blockIdx.x * (256 * RNK_RPT) + tid;
    #pragma unroll
    for (int r = 0; r < RNK_RPT; ++r) {
        int e = base + r * 256;
        mine[r] = (e < PRE_NMS) ? keys[e] : 0;
        rank[r] = 0;
    }
    for (int c0 = 0; c0 < PRE_NMS; c0 += 2048) {
        for (int j = tid; j < 2048; j += 256) {
            int g = c0 + j;
            ch[j] = (g < PRE_NMS) ? keys[g] : 0;
        }
        __syncthreads();
        #pragma unroll 8
        for (int j = 0; j < 2048; ++j) {
            uint64_t kj = ch[j];
            #pragma unroll
            for (int r = 0; r < RNK_RPT; ++r) rank[r] += (kj > mine[r]) ? 1 : 0;
        }
        __syncthreads();
    }
    #pragma unroll
    for (int r = 0; r < RNK_RPT; ++r) {
        int e = base + r * 256;
        if (e < PRE_NMS) aidx[(size_t)b * PRE_NMS + rank[r]] = ~(uint32_t)(mine[r] & 0xFFFFFFFFull);
    }
}

// ---------- gather + bbox decode + clip (rank order) ----------
__global__ void k_gather(const float4* __restrict__ anchors, const float4* __restrict__ deltas,
                         const float* __restrict__ im_info, const uint32_t* __restrict__ aidx,
                         float4* __restrict__ props) {
    int b = blockIdx.y;
    int i = blockIdx.x * 256 + threadIdx.x;
    if (i >= PRE_NMS) return;
    uint32_t a = aidx[(size_t)b * PRE_NMS + i];
    float4 an = anchors[a];
    float4 dl = deltas[(size_t)b * NANCH + a];
    float w  = __fadd_rn(__fsub_rn(an.z, an.x), 1.0f);
    float h  = __fadd_rn(__fsub_rn(an.w, an.y), 1.0f);
    float cx = __fadd_rn(an.x, __fmul_rn(0.5f, w));
    float cy = __fadd_rn(an.y, __fmul_rn(0.5f, h));
    float pcx = __fadd_rn(__fmul_rn(dl.x, w), cx);
    float pcy = __fadd_rn(__fmul_rn(dl.y, h), cy);
    float ew = (float)exp((double)dl.z);
    float eh = (float)exp((double)dl.w);
    float pw = __fmul_rn(ew, w);
    float ph = __fmul_rn(eh, h);
    float x1 = __fsub_rn(pcx, __fmul_rn(0.5f, pw));
    float y1 = __fsub_rn(pcy, __fmul_rn(0.5f, ph));
    float x2 = __fadd_rn(pcx, __fmul_rn(0.5f, pw));
    float y2 = __fadd_rn(pcy, __fmul_rn(0.5f, ph));
    float xmax = __fsub_rn(im_info[b * 3 + 1], 1.0f);
    float ymax = __fsub_rn(im_info[b * 3 + 0], 1.0f);
    x1 = fminf(fmaxf(x1, 0.0f), xmax);
    y1 = fminf(fmaxf(y1, 0.0f), ymax);
    x2 = fminf(fmaxf(x2, 0.0f), xmax);
    y2 = fminf(fmaxf(y2, 0.0f), ymax);
    props[(size_t)b * PRE_NMS + i] = make_float4(x1, y1, x2, y2);
}

// ---------- spatial binning helpers ----------
// bucket b = clamp(floor(log2(width)), 2, 9); grid b has cells of 2^(b+1) px.
// IoU>0.7 => width-ratio >= 0.678 => buckets differ by <= 1 (proven).
__device__ __forceinline__ int bucket_of(float w) {
    int iw = (int)w;                 // w >= 1
    int bb = 31 - __clz(iw);
    return min(max(bb, 2), 9);
}
__device__ __forceinline__ int grid_base(int g) {        // bins before grid g
    return (65536 - (65536 >> ((g - 2) * 2))) / 3;
}

// ---------- bin count / fill (insert box into its own bucket's grid) ----------
__global__ void k_bincnt(const float4* __restrict__ props, uint32_t* __restrict__ bincnt) {
    int b = blockIdx.y;
    int i = blockIdx.x * 256 + threadIdx.x;
    if (i >= PRE_NMS) return;
    float4 p = props[(size_t)b * PRE_NMS + i];
    float w = __fadd_rn(__fsub_rn(p.z, p.x), 1.0f);
    int bb = bucket_of(w);
    int cs = bb + 1, dim = 128 >> (bb - 2);
    uint32_t* cb = bincnt + (size_t)b * NBINS + grid_base(bb);
    int cx0 = ((int)p.x) >> cs, cx1 = ((int)p.z) >> cs;
    int cy0 = ((int)p.y) >> cs, cy1 = ((int)p.w) >> cs;
    for (int cy = cy0; cy <= cy1; ++cy)
        for (int cx = cx0; cx <= cx1; ++cx)
            atomicAdd(&cb[cy * dim + cx], 1u);
}

__global__ void k_binfill(const float4* __restrict__ props, uint32_t* __restrict__ bincur,
                          uint16_t* __restrict__ binlist) {
    int b = blockIdx.y;
    int i = blockIdx.x * 256 + threadIdx.x;
    if (i >= PRE_NMS) return;
    float4 p = props[(size_t)b * PRE_NMS + i];
    float w = __fadd_rn(__fsub_rn(p.z, p.x), 1.0f);
    int bb = bucket_of(w);
    int cs = bb + 1, dim = 128 >> (bb - 2);
    uint32_t* cb = bincur + (size_t)b * NBINS + grid_base(bb);
    uint16_t* bl = binlist + (size_t)b * BINCAP;
    int cx0 = ((int)p.x) >> cs, cx1 = ((int)p.z) >> cs;
    int cy0 = ((int)p.y) >> cs, cy1 = ((int)p.w) >> cs;
    for (int cy = cy0; cy <= cy1; ++cy)
        for (int cx = cx0; cx <= cx1; ++cx) {
            uint32_t pos = atomicAdd(&cb[cy * dim + cx], 1u);
            if (pos < BINCAP) bl[pos] = (uint16_t)i;
        }
}

// ---------- per-batch exclusive scan of bin counts -> offsets; reset cursor ----
__global__ __launch_bounds__(1024) void k_binscan(uint32_t* bincnt, uint32_t* binoff) {
    __shared__ uint32_t wsum[16];
    int b = blockIdx.x, t = threadIdx.x, wv = t >> 6, ln = t & 63;
    uint32_t* cntb = bincnt + (size_t)b * NBINS;
    uint32_t* offb = binoff + (size_t)b * (NBINS + 1);
    const int PER = 22;                          // 22*1024 >= 21845
    int i0 = t * PER;
    uint32_t v[PER];
    uint32_t tot = 0;
    #pragma unroll
    for (int k = 0; k < PER; ++k) { int i = i0 + k; v[k] = (i < NBINS) ? cntb[i] : 0; tot += v[k]; }
    uint32_t x = tot;
    for (int d = 1; d < 64; d <<= 1) { uint32_t y = __shfl_up(x, d); if (ln >= d) x += y; }
    if (ln == 63) wsum[wv] = x;
    __syncthreads();
    uint32_t wb = 0;
    for (int w = 0; w < 16; ++w) wb += (w < wv) ? wsum[w] : 0u;
    uint32_t run = wb + x - tot;
    #pragma unroll
    for (int k = 0; k < PER; ++k) {
        int i = i0 + k;
        if (i < NBINS) { offb[i] = run; cntb[i] = run; run += v[k]; }
    }
    if (t == 1023) offb[NBINS] = run;
}

// ---------- per-batch exclusive scan of degrees -> CSR offsets ----------
__global__ __launch_bounds__(1024) void k_degscan(const uint32_t* deg, uint32_t* degoff) {
    __shared__ uint32_t wsum[16];
    int b = blockIdx.x, t = threadIdx.x, wv = t >> 6, ln = t & 63;
    const uint32_t* db = deg + (size_t)b * PRE_NMS;
    uint32_t* ob = degoff + (size_t)b * (PRE_NMS + 1);
    const int PER = 12;                          // 12*1024 >= 12000
    int i0 = t * PER;
    uint32_t v[PER];
    uint32_t tot = 0;
    #pragma unroll
    for (int k = 0; k < PER; ++k) { int i = i0 + k; v[k] = (i < PRE_NMS) ? db[i] : 0; tot += v[k]; }
    uint32_t x = tot;
    for (int d = 1; d < 64; d <<= 1) { uint32_t y = __shfl_up(x, d); if (ln >= d) x += y; }
    if (ln == 63) wsum[wv] = x;
    __syncthreads();
    uint32_t wb = 0;
    for (int w = 0; w < 16; ++w) wb += (w < wv) ? wsum[w] : 0u;
    uint32_t run = wb + x - tot;
    #pragma unroll
    for (int k = 0; k < PER; ++k) {
        int i = i0 + k;
        if (i < PRE_NMS) { ob[i] = run; run += v[k]; }
    }
    if (t == 1023) ob[PRE_NMS] = run;
}

// ---------- kill-graph search: count (FILL=0) / fill (FILL=1) ----------
// Box i searches grids [b-1,b+1], cells overlapping its rect expanded +-1px
// (captures the +1-convention overlap of near-disjoint rects). Dedup: pair
// (i,j) processed only at cell (max(sy0,jcy0), max(sx0,jcx0)) of grid b_j.
// Gates (safe, proven): width-ratio & height-ratio >= 0.678 needed for kill;
// gate at 0.6 for fp margin. Then exact IoU test.
template <int FILL>
__global__ __launch_bounds__(256) void k_search(const float4* __restrict__ props,
                                                const uint32_t* __restrict__ binoff,
                                                const uint16_t* __restrict__ binlist,
                                                uint32_t* __restrict__ deg,
                                                const uint32_t* __restrict__ degoff,
                                                uint16_t* __restrict__ adj) {
    int b = blockIdx.y;
    int i = blockIdx.x * 256 + threadIdx.x;
    if (i >= PRE_NMS) return;
    const float4* pb = props + (size_t)b * PRE_NMS;
    float4 pi = pb[i];
    float wi = __fadd_rn(__fsub_rn(pi.z, pi.x), 1.0f);
    float hi = __fadd_rn(__fsub_rn(pi.w, pi.y), 1.0f);
    int bb = bucket_of(wi);
    const uint32_t* ob = binoff + (size_t)b * (NBINS + 1);
    const uint16_t* bl = binlist + (size_t)b * BINCAP;
    uint32_t wrbase = 0;
    if (FILL) wrbase = degoff[(size_t)b * (PRE_NMS + 1) + i];
    uint16_t* adjb = adj + (size_t)b * ADJCAP;
    int cnt = 0;
    int g0 = max(2, bb - 1), g1 = min(9, bb + 1);
    float ex0 = fmaxf(__fsub_rn(pi.x, 1.0f), 0.0f);
    float ey0 = fmaxf(__fsub_rn(pi.y, 1.0f), 0.0f);
    float ex1 = fminf(__fadd_rn(pi.z, 1.0f), 1023.0f);
    float ey1 = fminf(__fadd_rn(pi.w, 1.0f), 1023.0f);
    for (int g = g0; g <= g1; ++g) {
        int cs = g + 1, dim = 128 >> (g - 2);
        int gb = grid_base(g);
        int sx0 = ((int)ex0) >> cs, sx1 = ((int)ex1) >> cs;
        int sy0 = ((int)ey0) >> cs, sy1 = ((int)ey1) >> cs;
        for (int cy = sy0; cy <= sy1; ++cy)
            for (int cx = sx0; cx <= sx1; ++cx) {
                int bin = gb + cy * dim + cx;
                uint32_t k0 = ob[bin], k1 = ob[bin + 1];
                for (uint32_t k = k0; k < k1; ++k) {
                    int j = (int)bl[k];
                    if (j == i) continue;
                    float4 pj = pb[j];
                    int jcx0 = ((int)pj.x) >> cs;
                    int jcy0 = ((int)pj.y) >> cs;
                    if (cx != max(sx0, jcx0) || cy != max(sy0, jcy0)) continue;   // dedup
                    float wj = __fadd_rn(__fsub_rn(pj.z, pj.x), 1.0f);
                    float hj = __fadd_rn(__fsub_rn(pj.w, pj.y), 1.0f);
                    if (fminf(wi, wj) < 0.6f * fmaxf(wi, wj)) continue;
                    if (fminf(hi, hj) < 0.6f * fmaxf(hi, hj)) continue;
                    if (kill_pair(pi, pj)) {
                        if (FILL) {
                            uint32_t idx = wrbase + (uint32_t)cnt;
                            if (idx < ADJCAP) adjb[idx] = (uint16_t)j;
                        }
                        cnt++;
                    }
                }
            }
    }
    if (!FILL) deg[(size_t)b * PRE_NMS + i] = (uint32_t)cnt;
}

// ---------- greedy NMS on the sparse kill graph: 1 wave per image ----------
// Chunk of 64 ranks: in-chunk kill rows from adjacency; scalar 64-step resolve;
// accepted lanes clear their neighbors' bits in the LDS mask. Acceptances
// beyond 2000 are discarded (proven output-equivalent to reference's
// fixed-length-2000 scan).
__global__ __launch_bounds__(64) void k_greedy(const uint32_t* __restrict__ degoff,
                                               const uint16_t* __restrict__ adj,
                                               int* __restrict__ keep,
                                               int* __restrict__ nkeep) {
    int b = blockIdx.x;
    int ln = threadIdx.x;
    __shared__ uint32_t mask[375];                 // 12000 bits exactly
    for (int i = ln; i < 375; i += 64) mask[i] = 0xFFFFFFFFu;
    __syncthreads();
    const uint32_t* ob = degoff + (size_t)b * (PRE_NMS + 1);
    const uint16_t* adjb = adj + (size_t)b * ADJCAP;
    int* keepb = keep + b * 2048;
    int nsel = 0;
    for (int c = 0; c < NCHUNK && nsel < POST_NMS; ++c) {
        int r = c * 64 + ln;
        uint32_t o0 = 0, o1 = 0;
        if (r < PRE_NMS) { o0 = ob[r]; o1 = ob[r + 1]; }
        uint32_t base = (uint32_t)(c * 64);
        uint64_t K = 0;
        for (uint32_t k = o0; k < o1; ++k) {
            uint32_t d = (uint32_t)adjb[k] - base;
            if (d < 64u) K |= (1ull << d);
        }
        int vbit = 0;
        if (r < PRE_NMS) vbit = (int)((mask[r >> 5] >> (r & 31)) & 1u);
        uint64_t valid = (uint64_t)__ballot(vbit);
        uint32_t Klo = (uint32_t)K, Khi = (uint32_t)(K >> 32);
        #pragma unroll
        for (int s = 0; s < 64; ++s) {
            if ((valid >> s) & 1ull) {
                uint32_t kl = (uint32_t)__builtin_amdgcn_readlane((int)Klo, s);
                uint32_t kh = (uint32_t)__builtin_amdgcn_readlane((int)Khi, s);
                valid &= ~(((uint64_t)kh << 32) | (uint64_t)kl);
            }
        }
        uint64_t acc = valid;
        int cnt = __popcll(acc);
        int myacc = (int)((acc >> ln) & 1ull);
        uint64_t ltm = (ln == 0) ? 0ull : (~0ull >> (64 - ln));
        int pos = nsel + __popcll(acc & ltm);
        bool eff = myacc && (pos < POST_NMS);
        if (eff) {
            keepb[pos] = r;
            for (uint32_t k = o0; k < o1; ++k) {
                uint32_t e = (uint32_t)adjb[k];
                atomicAnd(&mask[e >> 5], ~(1u << (e & 31)));
            }
        }
        nsel += cnt;
        __syncthreads();   // 1 wave: compiles to lgkmcnt drain; orders kills vs next read
    }
    if (ln == 0) nkeep[b] = min(nsel, POST_NMS);
}

// ---------- output rows ----------
__global__ void k_out(const float4* __restrict__ props, const int* __restrict__ keep,
                      const int* __restrict__ nkeep, float* __restrict__ out) {
    int b = blockIdx.y;
    int i = blockIdx.x * 256 + threadIdx.x;
    if (i >= POST_NMS) return;
    int n = nkeep[b];
    float* row = out + ((size_t)b * POST_NMS + i) * 5;
    if (i < n) {
        int r = keep[b * 2048 + i];
        float4 p = props[(size_t)b * PRE_NMS + r];
        row[0] = (float)b; row[1] = p.x; row[2] = p.y; row[3] = p.z; row[4] = p.w;
    } else {
        row[0] = (float)b; row[1] = 0.0f; row[2] = 0.0f; row[3] = 0.0f; row[4] = 0.0f;
    }
}

extern "C" void kernel_launch(void* const* d_in, const int* in_sizes, int n_in,
                              void* d_out, int out_size, void* d_ws, size_t ws_size,
                              hipStream_t stream) {
    const float* scores  = (const float*)d_in[0];
    const float* deltas  = (const float*)d_in[1];
    const float* im_info = (const float*)d_in[2];
    const float* anchors = (const float*)d_in[3];
    float* out = (float*)d_out;

    uint8_t* w = (uint8_t*)d_ws;
    uint32_t* hist    = (uint32_t*)(w);                 // 16384
    uint64_t* prefix  = (uint64_t*)(w + 16384);         // 128
    uint32_t* kth     = (uint32_t*)(w + 16512);         // 64
    uint32_t* cnt     = (uint32_t*)(w + 16576);         // 64
    uint64_t* selk    = (uint64_t*)(w + 16640);         // 1,536,000 -> 1,552,640
    uint32_t* aidx    = (uint32_t*)(w + 1552640);       // 768,000   -> 2,320,640
    float*    props   = (float*)(w + 2320640);          // 3,072,000 -> 5,392,640
    uint32_t* bincnt  = (uint32_t*)(w + 5392640);       // 1,398,080 -> 6,790,720
    uint32_t* binoff  = (uint32_t*)(w + 6790720);       // 1,398,144 -> 8,188,864
    uint16_t* binlist = (uint16_t*)(w + 8188864);       // 3,145,728 -> 11,334,592
    uint32_t* deg     = (uint32_t*)(w + 11334592);      // 768,000   -> 12,102,592
    uint32_t* degoff  = (uint32_t*)(w + 12102592);      // 768,064   -> 12,870,656
    uint16_t* adj     = (uint16_t*)(w + 12870656);      // 4,194,304 -> 17,064,960
    int*      keep    = (int*)(w + 17064960);           // 131,072   -> 17,196,032
    int*      nkeep   = (int*)(w + 17196032);           // 64        -> 17,196,096

    hipLaunchKernelGGL(k_init, dim3(256), dim3(256), 0, stream, hist, prefix, kth, cnt, bincnt);
    for (int p = 0; p < 8; ++p) {
        hipLaunchKernelGGL(k_hist, dim3(128, NBATCH), dim3(256), 0, stream, scores, hist, prefix, p);
        hipLaunchKernelGGL(k_pick, dim3(NBATCH), dim3(256), 0, stream, hist, prefix, kth, p);
    }
    hipLaunchKernelGGL(k_compact, dim3(128, NBATCH), dim3(256), 0, stream, scores, prefix, cnt, selk);
    hipLaunchKernelGGL(k_rank, dim3(12, NBATCH), dim3(256), 0, stream, selk, aidx);
    hipLaunchKernelGGL(k_gather, dim3(47, NBATCH), dim3(256), 0, stream,
                       (const float4*)anchors, (const float4*)deltas, im_info, aidx,
                       (float4*)props);
    hipLaunchKernelGGL(k_bincnt, dim3(47, NBATCH), dim3(256), 0, stream,
                       (const float4*)props, bincnt);
    hipLaunchKernelGGL(k_binscan, dim3(NBATCH), dim3(1024), 0, stream, bincnt, binoff);
    hipLaunchKernelGGL(k_binfill, dim3(47, NBATCH), dim3(256), 0, stream,
                       (const float4*)props, bincnt, binlist);
    hipLaunchKernelGGL(k_search<0>, dim3(47, NBATCH), dim3(256), 0, stream,
                       (const float4*)props, binoff, binlist, deg, degoff, adj);
    hipLaunchKernelGGL(k_degscan, dim3(NBATCH), dim3(1024), 0, stream, deg, degoff);
    hipLaunchKernelGGL(k_search<1>, dim3(47, NBATCH), dim3(256), 0, stream,
                       (const float4*)props, binoff, binlist, deg, degoff, adj);
    hipLaunchKernelGGL(k_greedy, dim3(NBATCH), dim3(64), 0, stream, degoff, adj, keep, nkeep);
    hipLaunchKernelGGL(k_out, dim3(8, NBATCH), dim3(256), 0, stream,
                       (const float4*)props, keep, nkeep, out);
}